// Round 3
// baseline (945.988 us; speedup 1.0000x reference)
//
#include <hip/hip_runtime.h>
#include <hip/hip_bf16.h>
#include <stdint.h>

// ---------------------------------------------------------------------------
// GCN: h1 = relu(adj @ (x @ W1) + b1); h2 = relu(adj @ (h1 @ W2) + b2)
//      out[b] = (sum_{n<len[b]} h2[b,n,:] / len[b]) @ Wl + bl
// B=64, N=1024, NFEAT=512, NHID1=1024, NHID2=512
//
// R2: 256^2/BK=64/8-wave 8-phase GEMM (T2 swizzle via pre-swizzled global
//     source, T3+T4 counted vmcnt, T5 setprio). 1023 -> 901 us.
// R3: pool fused into GEMM4 (early-exit dead rows), XCD z-swizzle, merged
//     conversions. 901 -> 808 us.
// R4: fp32->bf16 conversion pass ELIMINATED. G1 reads x fp32, G2/G4 read adj
//     fp32 directly: the fp32 operand is reg-staged (4x dwordx4 -> RNE pack
//     -> 2x ds_write_b128) with 1-tile lookahead; the bf16 operand keeps
//     global_load_lds. fp loads issued ph0/ph1, consumed ph2/ph3 (~2 phases
//     of MFMA cover HBM latency). vmcnt(0) only at tile boundary (2 trailing
//     glds). G3 (all-bf16) keeps the R2-verified template unchanged.
// ---------------------------------------------------------------------------

typedef short bf16x8 __attribute__((ext_vector_type(8)));
typedef short s16x4 __attribute__((ext_vector_type(4)));
typedef float f32x4 __attribute__((ext_vector_type(4)));

__device__ __forceinline__ unsigned short f2bf(float f) {
    union { float f; unsigned u; } v; v.f = f;
    unsigned r = v.u + 0x7fffu + ((v.u >> 16) & 1u);   // RNE
    return (unsigned short)(r >> 16);
}
__device__ __forceinline__ float bf2f(unsigned short h) {
    union { unsigned u; float f; } v; v.u = ((unsigned)h) << 16;
    return v.f;
}

__device__ __forceinline__ bf16x8 pack8(float4 a, float4 b) {
    bf16x8 o;
    o[0] = (short)f2bf(a.x); o[1] = (short)f2bf(a.y);
    o[2] = (short)f2bf(a.z); o[3] = (short)f2bf(a.w);
    o[4] = (short)f2bf(b.x); o[5] = (short)f2bf(b.y);
    o[6] = (short)f2bf(b.z); o[7] = (short)f2bf(b.w);
    return o;
}

typedef const __attribute__((address_space(1))) void* gp1_t;
typedef __attribute__((address_space(3))) void* lp3_t;

__device__ __forceinline__ void ldsload16(const void* g, void* l) {
    // dest = wave-uniform LDS base + lane*16 (HW semantics)
    __builtin_amdgcn_global_load_lds((gp1_t)(uintptr_t)g,
                                     (lp3_t)(unsigned)(uintptr_t)l,
                                     16, 0, 0);
}

// raw barrier + zero-cost compiler memory fence (pins LDS/VMEM ops to phases)
#define BARF()   do { __builtin_amdgcn_s_barrier(); asm volatile("" ::: "memory"); } while (0)
#define LGKM0()  asm volatile("s_waitcnt lgkmcnt(0)" ::: "memory")
#define VMCNT(n) asm volatile("s_waitcnt vmcnt(" #n ")" ::: "memory")
#define MFMA16(d, a, b) d = __builtin_amdgcn_mfma_f32_16x16x32_bf16(a, b, d, 0, 0, 0)

// ===========================================================================
// R2-verified all-bf16 template (used by GEMM3 only). Unchanged.
// ===========================================================================
template<bool BIASRELU, bool SPLIT, bool ZSWZ, bool POOL>
__global__ __launch_bounds__(512, 1)
void gemm_nt8(const short* __restrict__ A, const short* __restrict__ B,
              short* __restrict__ C, const float* __restrict__ bias,
              int M, int N, int K,
              long long aStride, long long bStride, long long cStride,
              long long splitStride,
              const int* __restrict__ length, float* __restrict__ pool_out)
{
    __shared__ short sm[2][2][256 * 64];

    int bx, by, bz;
    if (ZSWZ) {
        const int P = gridDim.x * gridDim.y;
        const int f = blockIdx.x + gridDim.x * (blockIdx.y + gridDim.y * blockIdx.z);
        const int k = f & 7;
        const int j = f >> 3;
        const int zper = gridDim.z >> 3;
        const int jp = j / P;
        bz = k * zper + jp;
        const int rem = j - jp * P;
        bx = rem % gridDim.x;
        by = rem / gridDim.x;
    } else {
        bx = blockIdx.x; by = blockIdx.y; bz = blockIdx.z;
    }

    const int bM = by * 256;
    const int bN = bx * 256;
    const int z  = bz;

    int len = 0;
    if (POOL) {
        len = length[z];
        if (bM >= len) return;
    }

    const int tid  = threadIdx.x;
    const int wid  = tid >> 6;
    const int lane = tid & 63;
    const int wm   = wid >> 2;
    const int wn   = wid & 3;
    const int quad = lane >> 4;
    const int l16  = lane & 15;

    A += (long long)z * aStride;
    B += (long long)z * bStride;

    const int srow = tid >> 3;
    const int scbs = ((tid & 7) * 16) ^ ((srow & 7) << 4);
    const short* Ag = A + (long long)(bM + srow) * K + (scbs >> 1);
    const short* Bg = B + (long long)(bN + srow) * K + (scbs >> 1);
    const long long row64  = 64LL * K;
    const long long row128 = 128LL * K;

    #define STAGE(buf, ab, h, kt) do {                                        \
        const short* g_ = (ab ? Bg : Ag) + (h ? row128 : 0) + (kt) * 64;      \
        char* l_ = (char*)&sm[buf][ab][0] + (h) * 16384 + wid * 1024;         \
        ldsload16(g_, l_);                                                    \
        ldsload16(g_ + row64, l_ + 8192);                                     \
    } while (0)

    const int cbs0 = (quad * 16) ^ ((l16 & 7) << 4);
    const int cbs1 = (64 + quad * 16) ^ ((l16 & 7) << 4);

    #define RDA(buf, m, kk) (*(const bf16x8*)((const char*)&sm[buf][0][0]     \
        + (wm * 128 + (m) * 16 + l16) * 128 + ((kk) ? cbs1 : cbs0)))
    #define RDB(buf, n, kk) (*(const bf16x8*)((const char*)&sm[buf][1][0]     \
        + (wn * 64 + (n) * 16 + l16) * 128 + ((kk) ? cbs1 : cbs0)))

    f32x4 acc[8][4];
#pragma unroll
    for (int m = 0; m < 8; ++m) {
#pragma unroll
        for (int n = 0; n < 4; ++n) acc[m][n] = (f32x4)0.0f;
    }

    const int NT = K >> 6;

    STAGE(0, 0, 0, 0); STAGE(0, 0, 1, 0);
    STAGE(0, 1, 0, 0); STAGE(0, 1, 1, 0);
    STAGE(1, 1, 0, 1); STAGE(1, 0, 0, 1);
    VMCNT(4);
    BARF();

    #define TILE_STEP(t, buf, bufn) do {                                      \
        int tn1 = (t) + 1; if (tn1 == NT) tn1 = 0;                            \
        int tn2 = (t) + 2; if (tn2 >= NT) tn2 -= NT;                          \
        bf16x8 a0[4], a1[4], p0[2], p1[2], q0[2], q1[2];                      \
        _Pragma("unroll") for (int m = 0; m < 4; ++m) {                       \
            a0[m] = RDA(buf, m, 0); a1[m] = RDA(buf, m, 1); }                 \
        _Pragma("unroll") for (int n = 0; n < 2; ++n) {                       \
            p0[n] = RDB(buf, n, 0); p1[n] = RDB(buf, n, 1); }                 \
        STAGE(bufn, 0, 1, tn1);                                               \
        BARF(); LGKM0();                                                      \
        __builtin_amdgcn_s_setprio(1);                                        \
        _Pragma("unroll") for (int m = 0; m < 4; ++m) {                       \
            _Pragma("unroll") for (int n = 0; n < 2; ++n) {                   \
                MFMA16(acc[m][n], a0[m], p0[n]);                              \
                MFMA16(acc[m][n], a1[m], p1[n]); } }                          \
        __builtin_amdgcn_s_setprio(0);                                        \
        BARF();                                                               \
        _Pragma("unroll") for (int n = 0; n < 2; ++n) {                       \
            q0[n] = RDB(buf, 2 + n, 0); q1[n] = RDB(buf, 2 + n, 1); }         \
        STAGE(bufn, 1, 1, tn1);                                               \
        BARF(); LGKM0();                                                      \
        __builtin_amdgcn_s_setprio(1);                                        \
        _Pragma("unroll") for (int m = 0; m < 4; ++m) {                       \
            _Pragma("unroll") for (int n = 0; n < 2; ++n) {                   \
                MFMA16(acc[m][2 + n], a0[m], q0[n]);                          \
                MFMA16(acc[m][2 + n], a1[m], q1[n]); } }                      \
        __builtin_amdgcn_s_setprio(0);                                        \
        BARF();                                                               \
        _Pragma("unroll") for (int m = 0; m < 4; ++m) {                       \
            a0[m] = RDA(buf, 4 + m, 0); a1[m] = RDA(buf, 4 + m, 1); }         \
        STAGE(buf, 1, 0, tn2);                                                \
        BARF(); LGKM0();                                                      \
        __builtin_amdgcn_s_setprio(1);                                        \
        _Pragma("unroll") for (int m = 0; m < 4; ++m) {                       \
            _Pragma("unroll") for (int n = 0; n < 2; ++n) {                   \
                MFMA16(acc[4 + m][2 + n], a0[m], q0[n]);                      \
                MFMA16(acc[4 + m][2 + n], a1[m], q1[n]); } }                  \
        __builtin_amdgcn_s_setprio(0);                                        \
        BARF();                                                               \
        STAGE(buf, 0, 0, tn2);                                                \
        BARF();                                                               \
        __builtin_amdgcn_s_setprio(1);                                        \
        _Pragma("unroll") for (int m = 0; m < 4; ++m) {                       \
            _Pragma("unroll") for (int n = 0; n < 2; ++n) {                   \
                MFMA16(acc[4 + m][n], a0[m], p0[n]);                          \
                MFMA16(acc[4 + m][n], a1[m], p1[n]); } }                      \
        __builtin_amdgcn_s_setprio(0);                                        \
        VMCNT(4);                                                             \
        BARF();                                                               \
    } while (0)

    for (int t = 0; t < NT; t += 2) {
        TILE_STEP(t, 0, 1);
        TILE_STEP(t + 1, 1, 0);
    }

    if (POOL) {
        VMCNT(0);
        __syncthreads();
        float* red = (float*)&sm[0][0][0];
#pragma unroll
        for (int n = 0; n < 4; ++n) {
            const int col = wn * 64 + n * 16 + l16;
            const float bv = bias[bN + col];
            float cs = 0.0f;
#pragma unroll
            for (int m = 0; m < 8; ++m) {
                const int row0 = bM + wm * 128 + m * 16 + quad * 4;
#pragma unroll
                for (int r = 0; r < 4; ++r) {
                    const float val = fmaxf(acc[m][n][r] + bv, 0.0f);
                    if (row0 + r < len) cs += val;
                }
            }
            cs += __shfl_xor(cs, 16);
            cs += __shfl_xor(cs, 32);
            if (quad == 0) red[wm * 256 + col] = cs;
        }
        __syncthreads();
        if (tid < 256) {
            const float s = red[tid] + red[256 + tid];
            pool_out[((long long)z * 4 + by) * 512 + bN + tid] = s;
        }
        return;
    }

#pragma unroll
    for (int m = 0; m < 8; ++m) {
        const int row0 = bM + wm * 128 + m * 16 + quad * 4;
#pragma unroll
        for (int n = 0; n < 4; ++n) {
            const int col = bN + wn * 64 + n * 16 + l16;
            float bv = 0.0f;
            if (BIASRELU) bv = bias[col];
#pragma unroll
            for (int r = 0; r < 4; ++r) {
                float val = acc[m][n][r];
                if (BIASRELU) val = fmaxf(val + bv, 0.0f);
                long long addr;
                if (SPLIT) {
                    const int bb = col >> 10;
                    const int nn = col & 1023;
                    addr = (long long)bb * splitStride
                         + (long long)(row0 + r) * 1024 + nn;
                } else {
                    addr = (long long)z * cStride
                         + (long long)(row0 + r) * N + col;
                }
                C[addr] = (short)f2bf(val);
            }
        }
    }
    #undef TILE_STEP
    #undef STAGE
    #undef RDA
    #undef RDB
}

// ===========================================================================
// Mixed-precision template: one operand fp32 (reg-staged + in-kernel RNE
// convert), the other bf16 via global_load_lds. FPS=0: A is fp32 (G2/G4);
// FPS=1: B is fp32 (G1). Staging is 1-tile-lookahead, same 8-phase MFMA
// interleave / swizzle / epilogue as the verified template above.
// ===========================================================================
template<bool BIASRELU, bool SPLIT, bool ZSWZ, bool POOL, int FPS>
__global__ __launch_bounds__(512, 2)
void gemm_ntf(const short* __restrict__ Xbf, const float* __restrict__ Xfp,
              short* __restrict__ C, const float* __restrict__ bias,
              int M, int N, int K,
              long long bfStride, long long fpStride, long long cStride,
              long long splitStride,
              const int* __restrict__ length, float* __restrict__ pool_out)
{
    __shared__ short sm[2][2][256 * 64];   // [buf][A=0/B=1][256][64] bf16

    int bx, by, bz;
    if (ZSWZ) {
        const int P = gridDim.x * gridDim.y;
        const int f = blockIdx.x + gridDim.x * (blockIdx.y + gridDim.y * blockIdx.z);
        const int k = f & 7;
        const int j = f >> 3;
        const int zper = gridDim.z >> 3;
        const int jp = j / P;
        bz = k * zper + jp;
        const int rem = j - jp * P;
        bx = rem % gridDim.x;
        by = rem / gridDim.x;
    } else {
        bx = blockIdx.x; by = blockIdx.y; bz = blockIdx.z;
    }

    const int bM = by * 256;
    const int bN = bx * 256;
    const int z  = bz;

    int len = 0;
    if (POOL) {
        len = length[z];
        if (bM >= len) return;
    }

    const int tid  = threadIdx.x;
    const int wid  = tid >> 6;
    const int lane = tid & 63;
    const int wm   = wid >> 2;
    const int wn   = wid & 3;
    const int quad = lane >> 4;
    const int l16  = lane & 15;

    constexpr int FP_SIDE = FPS;          // LDS tile index the fp operand fills
    constexpr int GL_SIDE = 1 - FPS;

    const int fpRow0 = (FPS == 0) ? bM : bN;
    const int glRow0 = (FPS == 0) ? bN : bM;

    // staging map: thread t covers row srow (and srow+64) of each 128-row
    // half, 8 elems at XOR-swizzled col (both-sides-or-neither, rule 21)
    const int srow = tid >> 3;
    const int scbs = ((tid & 7) * 16) ^ ((srow & 7) << 4);
    const short* Gbf = Xbf + (long long)z * bfStride
                     + (long long)(glRow0 + srow) * K + (scbs >> 1);
    const float* Gfp = Xfp + (long long)z * fpStride
                     + (long long)(fpRow0 + srow) * K + (scbs >> 1);
    const long long r64s  = 64LL * K;
    const long long r128s = 128LL * K;
    const long long r64f  = 64LL * K;
    const long long r128f = 128LL * K;

    // bf16 operand half-tile via 2 global_load_lds (2 vmcnt events)
    #define GLDSF(buf, h, kt) do {                                            \
        const short* g_ = Gbf + ((h) ? r128s : 0) + (long long)(kt) * 64;     \
        char* l_ = (char*)&sm[buf][GL_SIDE][0] + (h) * 16384 + wid * 1024;    \
        ldsload16(g_, l_);                                                    \
        ldsload16(g_ + r64s, l_ + 8192);                                      \
    } while (0)

    // fp32 operand half-tile: issue 4 float4 loads (rows srow, srow+64)
    #define FPISSUE(h, kt, ra, rb, rc, rd) do {                               \
        const float* f_ = Gfp + ((h) ? r128f : 0) + (long long)(kt) * 64;     \
        ra = *(const float4*)f_;       rb = *(const float4*)(f_ + 4);         \
        rc = *(const float4*)(f_ + r64f); rd = *(const float4*)(f_ + r64f + 4); \
    } while (0)

    // ...and later: pack + 2x ds_write_b128 into the linear LDS slots that
    // global_load_lds would have filled (same layout, same swizzle)
    #define FPWRITE(buf, h, ra, rb, rc, rd) do {                              \
        char* d_ = (char*)&sm[buf][FP_SIDE][0] + (h) * 16384 + tid * 16;      \
        *(bf16x8*)d_          = pack8(ra, rb);                                \
        *(bf16x8*)(d_ + 8192) = pack8(rc, rd);                                \
    } while (0)

    const int cbs0 = (quad * 16) ^ ((l16 & 7) << 4);
    const int cbs1 = (64 + quad * 16) ^ ((l16 & 7) << 4);

    #define RDAF(buf, m, kk) (*(const bf16x8*)((const char*)&sm[buf][0][0]    \
        + (wm * 128 + (m) * 16 + l16) * 128 + ((kk) ? cbs1 : cbs0)))
    #define RDBF(buf, n, kk) (*(const bf16x8*)((const char*)&sm[buf][1][0]    \
        + (wn * 64 + (n) * 16 + l16) * 128 + ((kk) ? cbs1 : cbs0)))

    #define MFMAQ(MO, NO, AA0, AA1, XX0, XX1)                                 \
        _Pragma("unroll") for (int m_ = 0; m_ < 4; ++m_) {                    \
            _Pragma("unroll") for (int n_ = 0; n_ < 2; ++n_) {                \
                MFMA16(acc[(MO) + m_][(NO) + n_], AA0[m_], XX0[n_]);          \
                MFMA16(acc[(MO) + m_][(NO) + n_], AA1[m_], XX1[n_]); } }

    f32x4 acc[8][4];
#pragma unroll
    for (int m = 0; m < 8; ++m) {
#pragma unroll
        for (int n = 0; n < 4; ++n) acc[m][n] = (f32x4)0.0f;
    }

    const int NT = K >> 6;   // 8 or 16 (even)

    // ---- prologue: tile 0 fully staged (issue order: fp h0, fp h1, glds x4)
    {
        float4 pa, pb, pc, pd, pe, pf, pg, ph;
        FPISSUE(0, 0, pa, pb, pc, pd);
        FPISSUE(1, 0, pe, pf, pg, ph);
        GLDSF(0, 0, 0); GLDSF(0, 1, 0);
        VMCNT(8);                     // fp-h0 landed
        FPWRITE(0, 0, pa, pb, pc, pd);
        VMCNT(4);                     // fp-h1 landed
        FPWRITE(0, 1, pe, pf, pg, ph);
        asm volatile("s_waitcnt vmcnt(0) lgkmcnt(0)" ::: "memory");
        BARF();
    }

    // ---- main loop: compute buf CUR, stage tile t+1 into buf NXT.
    // Per tile: ph0 {dsA m0-3 + dsB n0-1 | issue fp-h0 + glds-h0} MFMA(0,0)
    //           ph1 {dsB n2-3            | issue fp-h1 + glds-h1} MFMA(0,2)
    //           ph2 {dsA m4-7 | vm(8) pack+write fp-h0}           MFMA(4,2)
    //           ph3 {vm(2) pack+write fp-h1}  MFMA(4,0)  vm(0) barrier
    #define TSTEPF(t, CUR, NXT) do {                                          \
        int tn = (t) + 1; if (tn == NT) tn = 0;                               \
        bf16x8 a0[4], a1[4], p0[2], p1[2], q0[2], q1[2];                      \
        float4 fa, fb, fc, fd, fe, ff, fg, fh;                                \
        /* ph0 */                                                             \
        _Pragma("unroll") for (int m = 0; m < 4; ++m) {                       \
            a0[m] = RDAF(CUR, m, 0); a1[m] = RDAF(CUR, m, 1); }               \
        _Pragma("unroll") for (int n = 0; n < 2; ++n) {                       \
            p0[n] = RDBF(CUR, n, 0); p1[n] = RDBF(CUR, n, 1); }               \
        FPISSUE(0, tn, fa, fb, fc, fd);                                       \
        GLDSF(NXT, 0, tn);                                                    \
        BARF(); LGKM0();                                                      \
        __builtin_amdgcn_s_setprio(1);                                        \
        MFMAQ(0, 0, a0, a1, p0, p1);                                          \
        __builtin_amdgcn_s_setprio(0);                                        \
        BARF();                                                               \
        /* ph1 */                                                             \
        _Pragma("unroll") for (int n = 0; n < 2; ++n) {                       \
            q0[n] = RDBF(CUR, 2 + n, 0); q1[n] = RDBF(CUR, 2 + n, 1); }       \
        FPISSUE(1, tn, fe, ff, fg, fh);                                       \
        GLDSF(NXT, 1, tn);                                                    \
        BARF(); LGKM0();                                                      \
        __builtin_amdgcn_s_setprio(1);                                        \
        MFMAQ(0, 2, a0, a1, q0, q1);                                          \
        __builtin_amdgcn_s_setprio(0);                                        \
        BARF();                                                               \
        /* ph2 */                                                             \
        _Pragma("unroll") for (int m = 0; m < 4; ++m) {                       \
            a0[m] = RDAF(CUR, 4 + m, 0); a1[m] = RDAF(CUR, 4 + m, 1); }       \
        VMCNT(8);                                                             \
        FPWRITE(NXT, 0, fa, fb, fc, fd);                                      \
        BARF(); LGKM0();                                                      \
        __builtin_amdgcn_s_setprio(1);                                        \
        MFMAQ(4, 2, a0, a1, q0, q1);                                          \
        __builtin_amdgcn_s_setprio(0);                                        \
        BARF();                                                               \
        /* ph3 */                                                             \
        VMCNT(2);                                                             \
        FPWRITE(NXT, 1, fe, ff, fg, fh);                                      \
        BARF(); LGKM0();                                                      \
        __builtin_amdgcn_s_setprio(1);                                        \
        MFMAQ(4, 0, a0, a1, p0, p1);                                          \
        __builtin_amdgcn_s_setprio(0);                                        \
        VMCNT(0);                                                             \
        BARF();                                                               \
    } while (0)

    for (int t = 0; t < NT; t += 2) {
        TSTEPF(t, 0, 1);
        TSTEPF(t + 1, 1, 0);
    }

    if (POOL) {
        VMCNT(0);
        __syncthreads();
        float* red = (float*)&sm[0][0][0];
#pragma unroll
        for (int n = 0; n < 4; ++n) {
            const int col = wn * 64 + n * 16 + l16;
            const float bv = bias[bN + col];
            float cs = 0.0f;
#pragma unroll
            for (int m = 0; m < 8; ++m) {
                const int row0 = bM + wm * 128 + m * 16 + quad * 4;
#pragma unroll
                for (int r = 0; r < 4; ++r) {
                    const float val = fmaxf(acc[m][n][r] + bv, 0.0f);
                    if (row0 + r < len) cs += val;
                }
            }
            cs += __shfl_xor(cs, 16);
            cs += __shfl_xor(cs, 32);
            if (quad == 0) red[wm * 256 + col] = cs;
        }
        __syncthreads();
        if (tid < 256) {
            const float s = red[tid] + red[256 + tid];
            pool_out[((long long)z * 4 + by) * 512 + bN + tid] = s;
        }
        return;
    }

#pragma unroll
    for (int m = 0; m < 8; ++m) {
        const int row0 = bM + wm * 128 + m * 16 + quad * 4;
#pragma unroll
        for (int n = 0; n < 4; ++n) {
            const int col = bN + wn * 64 + n * 16 + l16;
            float bv = 0.0f;
            if (BIASRELU) bv = bias[col];
#pragma unroll
            for (int r = 0; r < 4; ++r) {
                float val = acc[m][n][r];
                if (BIASRELU) val = fmaxf(val + bv, 0.0f);
                long long addr;
                if (SPLIT) {
                    const int bb = col >> 10;
                    const int nn = col & 1023;
                    addr = (long long)bb * splitStride
                         + (long long)(row0 + r) * 1024 + nn;
                } else {
                    addr = (long long)z * cStride
                         + (long long)(row0 + r) * N + col;
                }
                C[addr] = (short)f2bf(val);
            }
        }
    }
    #undef TSTEPF
    #undef GLDSF
    #undef FPISSUE
    #undef FPWRITE
    #undef RDAF
    #undef RDBF
    #undef MFMAQ
}

// in[R][C] fp32 -> out[C][R] bf16, 32x32 LDS-tiled (coalesced both sides)
__global__ void transpose_cvt(const float* __restrict__ in,
                              short* __restrict__ out, int R, int C)
{
    __shared__ float tile[32][33];
    const int bc = blockIdx.x * 32;
    const int br = blockIdx.y * 32;
    const int tx = threadIdx.x & 31;
    const int ty = threadIdx.x >> 5;
#pragma unroll
    for (int i = 0; i < 32; i += 8)
        tile[ty + i][tx] = in[(long long)(br + ty + i) * C + bc + tx];
    __syncthreads();
#pragma unroll
    for (int i = 0; i < 32; i += 8)
        out[(long long)(bc + ty + i) * R + br + tx] = (short)f2bf(tile[tx][ty + i]);
}

// final pool: sum live 256-row chunks, dot with Wl, divide by len, add bl
// part layout: [b][4][512] fp32, chunk mb valid iff mb*256 < len[b]
__global__ void pool_final3(const float* __restrict__ part,
                            const int* __restrict__ length,
                            const float* __restrict__ Wl,
                            const float* __restrict__ bl,
                            float* __restrict__ out)
{
    const int b = blockIdx.x;
    const int t = threadIdx.x;             // 0..255, 2 channels each
    const int len = length[b];
    const int mbmax = (len + 255) >> 8;
    float s0 = 0.0f, s1 = 0.0f;
    for (int mb = 0; mb < mbmax; mb++) {
        float2 v = ((const float2*)part)[(b * 4 + mb) * 256 + t];
        s0 += v.x; s1 += v.y;
    }
    float v = s0 * Wl[2 * t] + s1 * Wl[2 * t + 1];
#pragma unroll
    for (int off = 32; off > 0; off >>= 1) v += __shfl_down(v, off);
    __shared__ float wsum[4];
    if ((t & 63) == 0) wsum[t >> 6] = v;
    __syncthreads();
    if (t == 0) {
        float s = wsum[0] + wsum[1] + wsum[2] + wsum[3];
        out[b] = s / (float)len + bl[0];
    }
}

extern "C" void kernel_launch(void* const* d_in, const int* in_sizes, int n_in,
                              void* d_out, int out_size, void* d_ws, size_t ws_size,
                              hipStream_t stream)
{
    const float* x    = (const float*)d_in[0];   // [64,1024,512]
    const float* adj  = (const float*)d_in[1];   // [64,1024,1024]
    const int*   len  = (const int*)d_in[2];     // [64]
    const float* W1   = (const float*)d_in[3];   // [512,1024]
    const float* b1   = (const float*)d_in[4];   // [1024]
    const float* W2   = (const float*)d_in[5];   // [1024,512]
    const float* b2   = (const float*)d_in[6];   // [512]
    const float* Wl   = (const float*)d_in[7];   // [512]
    const float* bl   = (const float*)d_in[8];   // [1]
    float* out = (float*)d_out;

    // workspace layout (~317 MiB used)
    char* ws = (char*)d_ws;
    short* W1T  = (short*)(ws);                    //   1 MB  [1024,512] bf16
    short* W2T  = (short*)(ws + 1048576LL);        //   1 MB  [512,1024] bf16
    float* part = (float*)(ws + 2097152LL);        // 0.5 MB  [64][4][512] fp32
    short* S1T  = (short*)(ws + 16777216LL);       // 128 MB  [64][1024][1024] bf16
    short* h1   = (short*)(ws + 150994944LL);      // 128 MB  [64,1024,1024] bf16
    short* S2T  = (short*)(ws + 285212672LL);      //  32 MB  [64][512][1024] bf16

    // weight transposes (tiny)
    transpose_cvt<<<dim3(32, 16), 256, 0, stream>>>(W1, W1T, 512, 1024);   // -> [1024,512]
    transpose_cvt<<<dim3(16, 32), 256, 0, stream>>>(W2, W2T, 1024, 512);   // -> [512,1024]

    // GEMM1 (transposed, B=x fp32): S1T[b][h][n] = sum_f W1T[h][f] * x[b*1024+n][f]
    gemm_ntf<false, true, false, false, 1><<<dim3(256, 4, 1), 512, 0, stream>>>(
        W1T, x, S1T, nullptr, 1024, 65536, 512, 0, 0, 0, 1048576LL, nullptr, nullptr);

    // GEMM2 (A=adj fp32): h1[b][i][h] = relu(sum_j adj[b][i][j] * S1T[b][h][j] + b1[h])
    gemm_ntf<true, false, true, false, 0><<<dim3(4, 4, 64), 512, 0, stream>>>(
        S1T, adj, h1, b1, 1024, 1024, 1024, 1048576LL, 1048576LL, 1048576LL, 0, nullptr, nullptr);

    // GEMM3 (all-bf16, R2 template): S2T[b][h2][n] = sum_h W2T[h2][h] * h1[b*1024+n][h]
    gemm_nt8<false, true, false, false><<<dim3(256, 2, 1), 512, 0, stream>>>(
        W2T, h1, S2T, nullptr, 512, 65536, 1024, 0, 0, 0, 524288LL, nullptr, nullptr);

    // GEMM4 (A=adj fp32) + fused pool: part[b][mb][c] = sum_{rows<len} relu(adj@S2T + b2)
    gemm_ntf<true, false, true, true, 0><<<dim3(2, 4, 64), 512, 0, stream>>>(
        S2T, adj, nullptr, b2, 1024, 512, 1024, 524288LL, 1048576LL, 0, 0, len, part);

    // final pool reduction
    pool_final3<<<64, 256, 0, stream>>>(part, len, Wl, bl, out);
}